// Round 2
// baseline (375.672 us; speedup 1.0000x reference)
//
#include <hip/hip_runtime.h>
#include <hip/hip_bf16.h>
#include <cstdint>
#include <cstddef>

typedef unsigned short u16;
typedef __attribute__((ext_vector_type(8))) __bf16 bf16x8;
typedef __attribute__((ext_vector_type(16))) float f32x16;

#define LPOS 4096
#define CDIM 256

// async global->LDS 16B: LDS dst must be wave-uniform base + lane*16
#define GLOAD_LDS16(g, l)                                                      \
  __builtin_amdgcn_global_load_lds(                                            \
      (const __attribute__((address_space(1))) void*)(g),                      \
      (__attribute__((address_space(3))) void*)(l), 16, 0, 0)

__device__ __forceinline__ unsigned f2bfbits(float x) {
  union { float f; unsigned u; } v; v.f = x;
  return (v.u + 0x7FFFu + ((v.u >> 16) & 1u)) >> 16;
}
__device__ __forceinline__ unsigned packbf(float a, float b) {
  __hip_bfloat162 h2 = __float22bfloat162_rn(make_float2(a, b));
  return *(unsigned*)&h2;
}

// ---------------- P1: per-position mean + inv-L2-norm ----------------
__global__ void norm_stats(const float* __restrict__ t_in,
                           const float* __restrict__ s_in,
                           const float* __restrict__ r_in,
                           float* __restrict__ mArr, float* __restrict__ iArr) {
  int t = blockIdx.x * 256 + threadIdx.x;      // 0..24575
  int arr = t >> 13;
  int rem = t & 8191;
  int b = rem >> 12;
  int pos = rem & 4095;
  const float* inp = (arr == 0 ? t_in : arr == 1 ? s_in : r_in);
  const float* col = inp + (size_t)b * CDIM * LPOS + pos;
  float sum = 0.f, sumsq = 0.f;
#pragma unroll 8
  for (int c = 0; c < CDIM; ++c) {
    float v = col[(size_t)c * LPOS];
    sum += v; sumsq += v * v;
  }
  float mean = sum * (1.0f / CDIM);
  float nsq = sumsq - sum * sum * (1.0f / CDIM);
  float inv = rsqrtf(fmaxf(nsq, 1e-20f));
  mArr[t] = mean;
  iArr[t] = inv;
}

// ---------------- P2: normalize + transpose + cast to bf16 [B][L][C] --------
__global__ void norm_transpose(const float* __restrict__ t_in,
                               const float* __restrict__ s_in,
                               const float* __restrict__ r_in,
                               const float* __restrict__ mArr,
                               const float* __restrict__ iArr,
                               u16* __restrict__ qn, u16* __restrict__ ksn,
                               u16* __restrict__ krn) {
  int idx = blockIdx.x;
  int ab = idx >> 8;
  int arr = ab >> 1, b = ab & 1;
  int rr = idx & 255;
  int lt = rr & 63, ct = rr >> 6;
  int l0 = lt * 64, c0 = ct * 64;
  const float* inp = (arr == 0 ? t_in : arr == 1 ? s_in : r_in) + (size_t)b * CDIM * LPOS;
  u16* outp = (arr == 0 ? qn : arr == 1 ? ksn : krn) + (size_t)b * LPOS * CDIM;
  const float* m = mArr + (arr * 2 + b) * LPOS;
  const float* iv = iArr + (arr * 2 + b) * LPOS;
  __shared__ float lk[64][65];
  int t = threadIdx.x;
  int cq = t >> 6, ll = t & 63;
#pragma unroll
  for (int r2 = 0; r2 < 16; ++r2) {
    int cr = cq + r2 * 4;
    lk[cr][ll] = inp[(size_t)(c0 + cr) * LPOS + l0 + ll];
  }
  __syncthreads();
  int cp = t & 31, lb = t >> 5;
#pragma unroll
  for (int r2 = 0; r2 < 8; ++r2) {
    int l = lb + r2 * 8;
    int pos = l0 + l;
    float mm = m[pos], vv = iv[pos];
    float v0 = (lk[2 * cp][l] - mm) * vv;
    float v1 = (lk[2 * cp + 1][l] - mm) * vv;
    unsigned pk = packbf(v0, v1);
    *(unsigned*)&outp[(size_t)pos * CDIM + c0 + 2 * cp] = pk;
  }
}

// ---------------- P3: build combined V tensors (bf16, [C_v][L]) -------------
__global__ void build_v(const float* __restrict__ sf, const float* __restrict__ rf,
                        const float* __restrict__ sem,
                        u16* __restrict__ vs, u16* __restrict__ vr) {
  int t = blockIdx.x * 256 + threadIdx.x;
  const int NVS = 2 * 32 * 4096;
  if (t < NVS) {
    int b = t >> 17;
    int c = (t >> 12) & 31;
    int j = t & 4095;
    float v = (c < 4) ? sf[((size_t)b * 4 + c) * LPOS + j] : (c == 4 ? 1.0f : 0.0f);
    vs[t] = (u16)f2bfbits(v);
  } else {
    int t2 = t - NVS;
    if (t2 < 2 * 160 * 4096) {
      int b = t2 / (160 * 4096);
      int rr = t2 % (160 * 4096);
      int c = rr >> 12, j = rr & 4095;
      float v = (c < 151) ? sem[((size_t)b * 151 + c) * LPOS + j]
              : (c < 155) ? rf[((size_t)b * 4 + (c - 151)) * LPOS + j]
              : (c == 155) ? 1.0f : 0.0f;
      vr[((size_t)b * 192 + c) * LPOS + j] = (u16)f2bfbits(v);
    }
  }
}

// ---------------- fused flash soft-warp ----------------
// S^T orientation: D[m=j][n=i] = sum_c K[j][c] * Q[i][c]
// PV: D[m=c][n=i]  = sum_j V[c][j] * P[j][i]
template <int CT, bool IS_REF>
__device__ __forceinline__ void flash_body(
    const u16* __restrict__ qb, const u16* __restrict__ kb,
    const u16* __restrict__ vb, float* __restrict__ dst,
    u16* lds_k, u16* lds_v, int wave, int lane, int i_wave, int j_base, int iters) {
  int h = lane >> 5, ln = lane & 31;

  // Q fragments register-resident: B[k=c][n=i], lane n=ln, k = kt*16 + h*8 + t
  bf16x8 qf[16];
  const u16* qrow = qb + (size_t)(i_wave + ln) * CDIM;
#pragma unroll
  for (int kt = 0; kt < 16; ++kt)
    qf[kt] = *(const bf16x8*)(qrow + kt * 16 + h * 8);

  f32x16 O[CT];
#pragma unroll
  for (int c = 0; c < CT; ++c)
#pragma unroll
    for (int t = 0; t < 16; ++t) O[c][t] = 0.0f;

  for (int jt = 0; jt < iters; ++jt) {
    int j0 = j_base + jt * 32;
    __syncthreads();   // all waves done reading previous tile
    // --- async stage K tile [32 j][256 c], 16B chunks XOR-swizzled by (j&7)
    // LDS dst per lane = lds_k + (wave*4+g)*1024B + lane*16B (uniform+lane*16)
#pragma unroll
    for (int g = 0; g < 4; ++g) {
      int G = wave * 4 + g;
      int j = 2 * G + h;
      int mlog = ln ^ (j & 7);
      GLOAD_LDS16(kb + (size_t)(j0 + j) * CDIM + mlog * 8,
                  &lds_k[G * 512]);
    }
    // --- async stage V tile: planes p = j-octet, rows = c, 16B per (c,p)
    if (IS_REF) {
#pragma unroll
      for (int g = 0; g < 3; ++g) {
        int t2 = wave * 3 + g;              // 0..11
        int p = t2 & 3, cc = t2 >> 2;
        int c = cc * 64 + lane;             // 0..191
        GLOAD_LDS16(vb + (size_t)c * LPOS + j0 + p * 8,
                    &lds_v[p * 1536 + cc * 512]);
      }
    } else {
      if (wave < 2) {
        int p = wave * 2 + h;
        GLOAD_LDS16(vb + (size_t)ln * LPOS + j0 + p * 8,
                    &lds_v[wave * 512]);
      }
    }
    __syncthreads();   // compiler inserts s_waitcnt vmcnt(0) before s_barrier

    // QK: S^T tile, A = K (from LDS), B = Q (regs)
    f32x16 S;
#pragma unroll
    for (int t = 0; t < 16; ++t) S[t] = 0.0f;
#pragma unroll
    for (int kt = 0; kt < 16; ++kt) {
      int mphys = (2 * kt + h) ^ (ln & 7);
      bf16x8 ka = *(const bf16x8*)&lds_k[ln * CDIM + mphys * 8];
      S = __builtin_amdgcn_mfma_f32_32x32x16_bf16(ka, qf[kt], S, 0, 0, 0);
    }
    // scores are cosine sims in [-1,1]: exp directly, no max-subtract needed
#pragma unroll
    for (int t = 0; t < 16; ++t) S[t] = __expf(S[t]);

    // P^T C-layout -> PV B-frags via xor-32 lane exchange, cast to bf16
    bf16x8 pb[2];
#pragma unroll
    for (int kt = 0; kt < 2; ++kt) {
      int kbase = kt * 8 + (h ? 4 : 0);
      int sbase = kt * 8 + (h ? 0 : 4);
      unsigned keep0 = packbf(S[kbase + 0], S[kbase + 1]);
      unsigned keep1 = packbf(S[kbase + 2], S[kbase + 3]);
      unsigned send0 = packbf(S[sbase + 0], S[sbase + 1]);
      unsigned send1 = packbf(S[sbase + 2], S[sbase + 3]);
      unsigned recv0 = (unsigned)__shfl_xor((int)send0, 32, 64);
      unsigned recv1 = (unsigned)__shfl_xor((int)send1, 32, 64);
      union { unsigned u[4]; bf16x8 v; } tmp;
      tmp.u[0] = h ? recv0 : keep0;
      tmp.u[1] = h ? recv1 : keep1;
      tmp.u[2] = h ? keep0 : recv0;
      tmp.u[3] = h ? keep1 : recv1;
      pb[kt] = tmp.v;
    }

    // PV: A = V (from LDS planes), B = P
#pragma unroll
    for (int ct = 0; ct < CT; ++ct)
#pragma unroll
      for (int kt = 0; kt < 2; ++kt) {
        int p = 2 * kt + h;
        const u16* vp = IS_REF ? &lds_v[p * 1536 + (ct * 32 + ln) * 8]
                               : &lds_v[p * 256 + ln * 8];
        bf16x8 va = *(const bf16x8*)vp;
        O[ct] = __builtin_amdgcn_mfma_f32_32x32x16_bf16(va, pb[kt], O[ct], 0, 0, 0);
      }
  }

  // epilogue: D rows = c, cols = i
  if (IS_REF) {
#pragma unroll
    for (int ct = 0; ct < CT; ++ct)
#pragma unroll
      for (int t = 0; t < 16; ++t) {
        int c = ct * 32 + (t & 3) + 8 * (t >> 2) + 4 * h;
        dst[(size_t)c * LPOS + i_wave + ln] = O[ct][t];
      }
  } else {
#pragma unroll
    for (int t = 0; t < 4; ++t) {
      int c = t + 4 * h;
      dst[(size_t)c * LPOS + i_wave + ln] = O[0][t];
    }
  }
}

__global__ __launch_bounds__(256, 4) void flash(
    const u16* __restrict__ qn, const u16* __restrict__ ksn, const u16* __restrict__ krn,
    const u16* __restrict__ vs, const u16* __restrict__ vr,
    float* __restrict__ nsrc, float* __restrict__ nref, int nchunks) {
  __shared__ u16 lds_k[32 * 256];    // 16 KB
  __shared__ u16 lds_v[4 * 192 * 8]; // 12 KB
  int tid = threadIdx.x;
  int wave = tid >> 6, lane = tid & 63;
  int bpc = 64 * nchunks;
  int idx = blockIdx.x;
  bool is_ref = idx >= bpc;
  int r = is_ref ? idx - bpc : idx;
  int chunk = r >> 6;
  int b = (r >> 5) & 1;
  int wgi = r & 31;
  int jchunk = LPOS / nchunks;
  int j_base = chunk * jchunk;
  int iters = jchunk / 32;
  int i_wave = wgi * 128 + wave * 32;
  const u16* qb = qn + (size_t)b * LPOS * CDIM;
  if (is_ref) {
    flash_body<5, true>(qb, krn + (size_t)b * LPOS * CDIM, vr + (size_t)b * 192 * LPOS,
                        nref + (size_t)(chunk * 2 + b) * 160 * LPOS,
                        lds_k, lds_v, wave, lane, i_wave, j_base, iters);
  } else {
    flash_body<1, false>(qb, ksn + (size_t)b * LPOS * CDIM, vs + (size_t)b * 32 * LPOS,
                         nsrc + (size_t)(chunk * 2 + b) * 8 * LPOS,
                         lds_k, lds_v, wave, lane, i_wave, j_base, iters);
  }
}

// ---------------- finalize: sum chunks, divide by ones-channel --------------
__global__ void finalize(const float* __restrict__ nsrc, const float* __restrict__ nref,
                         float* __restrict__ out, int nchunks) {
  int t = blockIdx.x * 256 + threadIdx.x;
  if (t >= 1302528) return;
  if (t < 32768) {                        // warped_src_feat [2][4][4096]
    int b = t >> 14, c = (t >> 12) & 3, i = t & 4095;
    float num = 0.f, den = 0.f;
    for (int k = 0; k < nchunks; ++k) {
      const float* base = nsrc + ((size_t)(k * 2 + b) * 8) * LPOS;
      num += base[(size_t)c * LPOS + i];
      den += base[(size_t)4 * LPOS + i];
    }
    out[t] = num / den;
  } else if (t < 65536) {                 // warped_ref_feat [2][4][4096]
    int t1 = t - 32768;
    int b = t1 >> 14, c = (t1 >> 12) & 3, i = t1 & 4095;
    float num = 0.f, den = 0.f;
    for (int k = 0; k < nchunks; ++k) {
      const float* base = nref + ((size_t)(k * 2 + b) * 160) * LPOS;
      num += base[(size_t)(151 + c) * LPOS + i];
      den += base[(size_t)155 * LPOS + i];
    }
    out[t] = num / den;
  } else {                                // warped_ref_seg [2][151][4096]
    int t2 = t - 65536;
    int b = t2 / 618496;
    int rr = t2 % 618496;
    int c = rr >> 12, i = rr & 4095;
    float num = 0.f, den = 0.f;
    for (int k = 0; k < nchunks; ++k) {
      const float* base = nref + ((size_t)(k * 2 + b) * 160) * LPOS;
      num += base[(size_t)c * LPOS + i];
      den += base[(size_t)155 * LPOS + i];
    }
    out[t] = num / den;
  }
}

extern "C" void kernel_launch(void* const* d_in, const int* in_sizes, int n_in,
                              void* d_out, int out_size, void* d_ws, size_t ws_size,
                              hipStream_t stream) {
  const float* trg  = (const float*)d_in[0];
  const float* srcp = (const float*)d_in[1];
  const float* refp = (const float*)d_in[2];
  const float* sfeat = (const float*)d_in[3];
  const float* rfeat = (const float*)d_in[4];
  const float* rsem  = (const float*)d_in[5];
  float* out = (float*)d_out;

  char* ws = (char*)d_ws;
  size_t o = 0;
  auto alloc = [&](size_t bytes) -> char* {
    char* p = ws + o;
    o += (bytes + 255) & ~(size_t)255;
    return p;
  };
  u16* qn  = (u16*)alloc(2ull * LPOS * CDIM * 2);
  u16* ksn = (u16*)alloc(2ull * LPOS * CDIM * 2);
  u16* krn = (u16*)alloc(2ull * LPOS * CDIM * 2);
  u16* vs  = (u16*)alloc(2ull * 32 * LPOS * 2);
  u16* vr  = (u16*)alloc(2ull * 192 * LPOS * 2);
  float* mArr = (float*)alloc(3ull * 2 * LPOS * 4);
  float* iArr = (float*)alloc(3ull * 2 * LPOS * 4);

  size_t fixed = o;
  int nchunks = 8;              // 1024 WGs -> 4 blocks/CU
  while (nchunks > 1) {
    size_t need = fixed + 512 +
                  (size_t)nchunks * 2 * 8 * LPOS * 4 +
                  (size_t)nchunks * 2 * 160 * LPOS * 4;
    if (need <= ws_size) break;
    nchunks >>= 1;
  }
  float* nsrc = (float*)alloc((size_t)nchunks * 2 * 8 * LPOS * 4);
  float* nref = (float*)alloc((size_t)nchunks * 2 * 160 * LPOS * 4);

  hipLaunchKernelGGL(norm_stats, dim3(96), dim3(256), 0, stream,
                     trg, srcp, refp, mArr, iArr);
  hipLaunchKernelGGL(norm_transpose, dim3(1536), dim3(256), 0, stream,
                     trg, srcp, refp, mArr, iArr, qn, ksn, krn);
  hipLaunchKernelGGL(build_v, dim3(6144), dim3(256), 0, stream,
                     sfeat, rfeat, rsem, vs, vr);
  hipLaunchKernelGGL(flash, dim3(128 * nchunks), dim3(256), 0, stream,
                     qn, ksn, krn, vs, vr, nsrc, nref, nchunks);
  hipLaunchKernelGGL(finalize, dim3(5088), dim3(256), 0, stream,
                     nsrc, nref, out, nchunks);
}

// Round 3
// 221.783 us; speedup vs baseline: 1.6939x; 1.6939x over previous
//
#include <hip/hip_runtime.h>
#include <hip/hip_bf16.h>
#include <cstdint>
#include <cstddef>

typedef unsigned short u16;
typedef __attribute__((ext_vector_type(8))) __bf16 bf16x8;
typedef __attribute__((ext_vector_type(16))) float f32x16;

#define LPOS 4096
#define CDIM 256

// async global->LDS 16B: LDS dst must be wave-uniform base + lane*16
#define GLOAD_LDS16(g, l)                                                      \
  __builtin_amdgcn_global_load_lds(                                            \
      (const __attribute__((address_space(1))) void*)(g),                      \
      (__attribute__((address_space(3))) void*)(l), 16, 0, 0)

// fine-grained waitcnt: wait until <= N vector-memory ops outstanding.
// NEVER vmcnt(0) mid-loop: keeps the prefetch in flight across the barrier.
#define WAITVM(N) asm volatile("s_waitcnt vmcnt(" #N ")" ::: "memory")
// raw barrier (no compiler-inserted vmcnt(0) drain, unlike __syncthreads)
#define BARRIER_RAW() asm volatile("s_barrier" ::: "memory")
// barrier that also guarantees this wave's LDS reads have completed
#define BARRIER_LGKM() asm volatile("s_waitcnt lgkmcnt(0)\n\ts_barrier" ::: "memory")

__device__ __forceinline__ unsigned f2bfbits(float x) {
  union { float f; unsigned u; } v; v.f = x;
  return (v.u + 0x7FFFu + ((v.u >> 16) & 1u)) >> 16;
}
__device__ __forceinline__ unsigned packbf(float a, float b) {
  __hip_bfloat162 h2 = __float22bfloat162_rn(make_float2(a, b));
  return *(unsigned*)&h2;
}

// ------- fused normalize: stats + normalize + transpose + bf16 cast --------
// One block = 32 positions x 256 channels of one (arr,b). Input read ONCE.
// tile layout [c][32+1] floats: phase-1 write banks (c+pos)%32 conflict-free.
__global__ void norm_fused(const float* __restrict__ t_in,
                           const float* __restrict__ s_in,
                           const float* __restrict__ r_in,
                           u16* __restrict__ qn, u16* __restrict__ ksn,
                           u16* __restrict__ krn) {
  __shared__ float tile[256 * 33];
  __shared__ float sums[256], sqs[256];
  __shared__ float mv[32], ivv[32];
  int idx = blockIdx.x;
  int ab = idx >> 7, lt = idx & 127;
  int arr = ab >> 1, b = ab & 1;
  int l0 = lt * 32;
  const float* inp = (arr == 0 ? t_in : arr == 1 ? s_in : r_in) + (size_t)b * CDIM * LPOS;
  u16* outp = (arr == 0 ? qn : arr == 1 ? ksn : krn) + (size_t)b * LPOS * CDIM;
  int t = threadIdx.x;
  int cg = t >> 5, l = t & 31;          // 8 channel-groups x 32 positions
  float sum = 0.f, sq = 0.f;
#pragma unroll 8
  for (int cc = 0; cc < 32; ++cc) {
    int c = cg * 32 + cc;
    float v = inp[(size_t)c * LPOS + l0 + l];
    tile[c * 33 + l] = v;
    sum += v; sq += v * v;
  }
  sums[t] = sum; sqs[t] = sq;
  __syncthreads();
  if (t < 32) {
    float s = 0.f, q = 0.f;
#pragma unroll
    for (int g = 0; g < 8; ++g) { s += sums[g * 32 + t]; q += sqs[g * 32 + t]; }
    float mean = s * (1.0f / CDIM);
    float nsq = q - s * s * (1.0f / CDIM);
    mv[t] = mean;
    ivv[t] = rsqrtf(fmaxf(nsq, 1e-20f));
  }
  __syncthreads();
  int c2 = t & 127, ph = t >> 7;        // u32 (2-channel) coalesced stores
#pragma unroll 4
  for (int rr = 0; rr < 16; ++rr) {
    int pos = ph + rr * 2;
    float m = mv[pos], iv = ivv[pos];
    float v0 = (tile[(2 * c2) * 33 + pos] - m) * iv;
    float v1 = (tile[(2 * c2 + 1) * 33 + pos] - m) * iv;
    *(unsigned*)&outp[(size_t)(l0 + pos) * CDIM + 2 * c2] = packbf(v0, v1);
  }
}

// ---------------- build combined V tensors (bf16, [C_v][L]) -----------------
__global__ void build_v(const float* __restrict__ sf, const float* __restrict__ rf,
                        const float* __restrict__ sem,
                        u16* __restrict__ vs, u16* __restrict__ vr) {
  int t = blockIdx.x * 256 + threadIdx.x;
  const int NVS = 2 * 32 * 4096;
  if (t < NVS) {
    int b = t >> 17;
    int c = (t >> 12) & 31;
    int j = t & 4095;
    float v = (c < 4) ? sf[((size_t)b * 4 + c) * LPOS + j] : (c == 4 ? 1.0f : 0.0f);
    vs[t] = (u16)f2bfbits(v);
  } else {
    int t2 = t - NVS;
    if (t2 < 2 * 160 * 4096) {
      int b = t2 / (160 * 4096);
      int rr = t2 % (160 * 4096);
      int c = rr >> 12, j = rr & 4095;
      float v = (c < 151) ? sem[((size_t)b * 151 + c) * LPOS + j]
              : (c < 155) ? rf[((size_t)b * 4 + (c - 151)) * LPOS + j]
              : (c == 155) ? 1.0f : 0.0f;
      vr[((size_t)b * 192 + c) * LPOS + j] = (u16)f2bfbits(v);
    }
  }
}

// ---------------- fused flash soft-warp, double-buffered --------------------
// S^T orientation: D[m=j][n=i] = sum_c K[j][c] * Q[i][c]
// PV: D[m=c][n=i]  = sum_j V[c][j] * P[j][i]
template <int CT, bool IS_REF>
__device__ __forceinline__ void flash_body(
    const u16* __restrict__ qb, const u16* __restrict__ kb,
    const u16* __restrict__ vb, float* __restrict__ dst,
    u16 (*lds_k)[32 * 256], u16 (*lds_v)[4 * 192 * 8],
    int wave, int lane, int i_wave, int j_base, int iters) {
  int h = lane >> 5, ln = lane & 31;

  // Q fragments register-resident: B[k=c][n=i], lane n=ln, k = kt*16 + h*8 + t
  bf16x8 qf[16];
  const u16* qrow = qb + (size_t)(i_wave + ln) * CDIM;
#pragma unroll
  for (int kt = 0; kt < 16; ++kt)
    qf[kt] = *(const bf16x8*)(qrow + kt * 16 + h * 8);

  f32x16 O[CT];
#pragma unroll
  for (int c = 0; c < CT; ++c)
#pragma unroll
    for (int t = 0; t < 16; ++t) O[c][t] = 0.0f;

  auto stage = [&](int j0, int buf) {
#pragma unroll
    for (int g = 0; g < 4; ++g) {
      int G = wave * 4 + g;
      int j = 2 * G + h;
      int mlog = ln ^ (j & 7);
      GLOAD_LDS16(kb + (size_t)(j0 + j) * CDIM + mlog * 8, &lds_k[buf][G * 512]);
    }
    if (IS_REF) {
#pragma unroll
      for (int g = 0; g < 3; ++g) {
        int t2 = wave * 3 + g;              // 0..11
        int p = t2 & 3, cc = t2 >> 2;
        int c = cc * 64 + lane;             // 0..191
        GLOAD_LDS16(vb + (size_t)c * LPOS + j0 + p * 8, &lds_v[buf][p * 1536 + cc * 512]);
      }
    } else {
      if (wave < 2) {
        int p = wave * 2 + h;
        GLOAD_LDS16(vb + (size_t)ln * LPOS + j0 + p * 8, &lds_v[buf][wave * 512]);
      }
    }
  };

  stage(j_base, 0);

  for (int jt = 0; jt < iters; ++jt) {
    int cur = jt & 1;
    if (jt + 1 < iters) {
      stage(j_base + (jt + 1) * 32, cur ^ 1);   // prefetch stays in flight
      if (IS_REF)        { WAITVM(7); }         // drain only tile jt's loads
      else if (wave < 2) { WAITVM(5); }
      else               { WAITVM(4); }
    } else {
      WAITVM(0);
    }
    BARRIER_RAW();    // tile jt visible to all waves; prefetch NOT drained
    const u16* lk = lds_k[cur];
    const u16* lv = lds_v[cur];

    // QK: S^T tile, A = K (from LDS), B = Q (regs); 2-way split acc chain
    f32x16 Sa, Sb;
#pragma unroll
    for (int t = 0; t < 16; ++t) { Sa[t] = 0.0f; Sb[t] = 0.0f; }
#pragma unroll
    for (int kt = 0; kt < 16; kt += 2) {
      int m0 = (2 * kt + h) ^ (ln & 7);
      bf16x8 ka0 = *(const bf16x8*)&lk[ln * CDIM + m0 * 8];
      Sa = __builtin_amdgcn_mfma_f32_32x32x16_bf16(ka0, qf[kt], Sa, 0, 0, 0);
      int m1 = (2 * (kt + 1) + h) ^ (ln & 7);
      bf16x8 ka1 = *(const bf16x8*)&lk[ln * CDIM + m1 * 8];
      Sb = __builtin_amdgcn_mfma_f32_32x32x16_bf16(ka1, qf[kt + 1], Sb, 0, 0, 0);
    }
    // cosine sims in [-1,1]: exp directly, no max-subtract needed
    f32x16 S;
#pragma unroll
    for (int t = 0; t < 16; ++t) S[t] = __expf(Sa[t] + Sb[t]);

    // P^T C-layout -> PV B-frags via xor-32 lane exchange, cast to bf16
    bf16x8 pb[2];
#pragma unroll
    for (int kt = 0; kt < 2; ++kt) {
      int kbase = kt * 8 + (h ? 4 : 0);
      int sbase = kt * 8 + (h ? 0 : 4);
      unsigned keep0 = packbf(S[kbase + 0], S[kbase + 1]);
      unsigned keep1 = packbf(S[kbase + 2], S[kbase + 3]);
      unsigned send0 = packbf(S[sbase + 0], S[sbase + 1]);
      unsigned send1 = packbf(S[sbase + 2], S[sbase + 3]);
      unsigned recv0 = (unsigned)__shfl_xor((int)send0, 32, 64);
      unsigned recv1 = (unsigned)__shfl_xor((int)send1, 32, 64);
      union { unsigned u[4]; bf16x8 v; } tmp;
      tmp.u[0] = h ? recv0 : keep0;
      tmp.u[1] = h ? recv1 : keep1;
      tmp.u[2] = h ? keep0 : recv0;
      tmp.u[3] = h ? keep1 : recv1;
      pb[kt] = tmp.v;
    }

    // PV: A = V (from LDS planes), B = P
#pragma unroll
    for (int ct = 0; ct < CT; ++ct)
#pragma unroll
      for (int kt = 0; kt < 2; ++kt) {
        int p = 2 * kt + h;
        const u16* vp = IS_REF ? &lv[p * 1536 + (ct * 32 + ln) * 8]
                               : &lv[p * 256 + ln * 8];
        bf16x8 va = *(const bf16x8*)vp;
        O[ct] = __builtin_amdgcn_mfma_f32_32x32x16_bf16(va, pb[kt], O[ct], 0, 0, 0);
      }

    BARRIER_LGKM();   // all waves done reading buf cur -> free for prefetch
  }

  // epilogue: D rows = c, cols = i
  if (IS_REF) {
#pragma unroll
    for (int ct = 0; ct < CT; ++ct)
#pragma unroll
      for (int t = 0; t < 16; ++t) {
        int c = ct * 32 + (t & 3) + 8 * (t >> 2) + 4 * h;
        dst[(size_t)c * LPOS + i_wave + ln] = O[ct][t];
      }
  } else {
#pragma unroll
    for (int t = 0; t < 4; ++t) {
      int c = t + 4 * h;
      dst[(size_t)c * LPOS + i_wave + ln] = O[0][t];
    }
  }
}

// block=256: __launch_bounds__(256,2) -> 256 VGPR/wave, NO spills.
// (256,4) in round 2 spilled Q-frags -> 533 MB scratch fetch, 2x regression.
__global__ __launch_bounds__(256, 2) void flash(
    const u16* __restrict__ qn, const u16* __restrict__ ksn, const u16* __restrict__ krn,
    const u16* __restrict__ vs, const u16* __restrict__ vr,
    float* __restrict__ nsrc, float* __restrict__ nref, int nchunks) {
  __shared__ u16 lds_k[2][32 * 256];    // 2 x 16 KB, double-buffered
  __shared__ u16 lds_v[2][4 * 192 * 8]; // 2 x 12 KB
  int tid = threadIdx.x;
  int wave = tid >> 6, lane = tid & 63;
  int bpc = 64 * nchunks;
  int idx = blockIdx.x;
  bool is_ref = idx >= bpc;
  int r = is_ref ? idx - bpc : idx;
  int chunk = r >> 6;
  int b = (r >> 5) & 1;
  int wgi = r & 31;
  int jchunk = LPOS / nchunks;
  int j_base = chunk * jchunk;
  int iters = jchunk / 32;
  int i_wave = wgi * 128 + wave * 32;
  const u16* qb = qn + (size_t)b * LPOS * CDIM;
  if (is_ref) {
    flash_body<5, true>(qb, krn + (size_t)b * LPOS * CDIM, vr + (size_t)b * 192 * LPOS,
                        nref + (size_t)(chunk * 2 + b) * 160 * LPOS,
                        lds_k, lds_v, wave, lane, i_wave, j_base, iters);
  } else {
    flash_body<1, false>(qb, ksn + (size_t)b * LPOS * CDIM, vs + (size_t)b * 32 * LPOS,
                         nsrc + (size_t)(chunk * 2 + b) * 8 * LPOS,
                         lds_k, lds_v, wave, lane, i_wave, j_base, iters);
  }
}

// ---------------- finalize: sum chunks, divide by ones-channel --------------
__global__ void finalize(const float* __restrict__ nsrc, const float* __restrict__ nref,
                         float* __restrict__ out, int nchunks) {
  int t = blockIdx.x * 256 + threadIdx.x;
  if (t >= 1302528) return;
  if (t < 32768) {                        // warped_src_feat [2][4][4096]
    int b = t >> 14, c = (t >> 12) & 3, i = t & 4095;
    float num = 0.f, den = 0.f;
    for (int k = 0; k < nchunks; ++k) {
      const float* base = nsrc + ((size_t)(k * 2 + b) * 8) * LPOS;
      num += base[(size_t)c * LPOS + i];
      den += base[(size_t)4 * LPOS + i];
    }
    out[t] = num / den;
  } else if (t < 65536) {                 // warped_ref_feat [2][4][4096]
    int t1 = t - 32768;
    int b = t1 >> 14, c = (t1 >> 12) & 3, i = t1 & 4095;
    float num = 0.f, den = 0.f;
    for (int k = 0; k < nchunks; ++k) {
      const float* base = nref + ((size_t)(k * 2 + b) * 160) * LPOS;
      num += base[(size_t)(151 + c) * LPOS + i];
      den += base[(size_t)155 * LPOS + i];
    }
    out[t] = num / den;
  } else {                                // warped_ref_seg [2][151][4096]
    int t2 = t - 65536;
    int b = t2 / 618496;
    int rr = t2 % 618496;
    int c = rr >> 12, i = rr & 4095;
    float num = 0.f, den = 0.f;
    for (int k = 0; k < nchunks; ++k) {
      const float* base = nref + ((size_t)(k * 2 + b) * 160) * LPOS;
      num += base[(size_t)c * LPOS + i];
      den += base[(size_t)155 * LPOS + i];
    }
    out[t] = num / den;
  }
}

extern "C" void kernel_launch(void* const* d_in, const int* in_sizes, int n_in,
                              void* d_out, int out_size, void* d_ws, size_t ws_size,
                              hipStream_t stream) {
  const float* trg  = (const float*)d_in[0];
  const float* srcp = (const float*)d_in[1];
  const float* refp = (const float*)d_in[2];
  const float* sfeat = (const float*)d_in[3];
  const float* rfeat = (const float*)d_in[4];
  const float* rsem  = (const float*)d_in[5];
  float* out = (float*)d_out;

  char* ws = (char*)d_ws;
  size_t o = 0;
  auto alloc = [&](size_t bytes) -> char* {
    char* p = ws + o;
    o += (bytes + 255) & ~(size_t)255;
    return p;
  };
  u16* qn  = (u16*)alloc(2ull * LPOS * CDIM * 2);
  u16* ksn = (u16*)alloc(2ull * LPOS * CDIM * 2);
  u16* krn = (u16*)alloc(2ull * LPOS * CDIM * 2);
  u16* vs  = (u16*)alloc(2ull * 32 * LPOS * 2);
  u16* vr  = (u16*)alloc(2ull * 192 * LPOS * 2);

  size_t fixed = o;
  int nchunks = 4;
  while (nchunks > 1) {
    size_t need = fixed + 512 +
                  (size_t)nchunks * 2 * 8 * LPOS * 4 +
                  (size_t)nchunks * 2 * 160 * LPOS * 4;
    if (need <= ws_size) break;
    nchunks >>= 1;
  }
  float* nsrc = (float*)alloc((size_t)nchunks * 2 * 8 * LPOS * 4);
  float* nref = (float*)alloc((size_t)nchunks * 2 * 160 * LPOS * 4);

  hipLaunchKernelGGL(norm_fused, dim3(768), dim3(256), 0, stream,
                     trg, srcp, refp, qn, ksn, krn);
  hipLaunchKernelGGL(build_v, dim3(6144), dim3(256), 0, stream,
                     sfeat, rfeat, rsem, vs, vr);
  hipLaunchKernelGGL(flash, dim3(128 * nchunks), dim3(256), 0, stream,
                     qn, ksn, krn, vs, vr, nsrc, nref, nchunks);
  hipLaunchKernelGGL(finalize, dim3(5088), dim3(256), 0, stream,
                     nsrc, nref, out, nchunks);
}

// Round 4
// 216.960 us; speedup vs baseline: 1.7315x; 1.0222x over previous
//
#include <hip/hip_runtime.h>
#include <hip/hip_bf16.h>
#include <cstdint>
#include <cstddef>

typedef unsigned short u16;
typedef __attribute__((ext_vector_type(8))) __bf16 bf16x8;
typedef __attribute__((ext_vector_type(16))) float f32x16;

#define LPOS 4096
#define CDIM 256

// async global->LDS 16B: LDS dst must be wave-uniform base + lane*16
#define GLOAD_LDS16(g, l)                                                      \
  __builtin_amdgcn_global_load_lds(                                            \
      (const __attribute__((address_space(1))) void*)(g),                      \
      (__attribute__((address_space(3))) void*)(l), 16, 0, 0)

__device__ __forceinline__ unsigned f2bfbits(float x) {
  union { float f; unsigned u; } v; v.f = x;
  return (v.u + 0x7FFFu + ((v.u >> 16) & 1u)) >> 16;
}
__device__ __forceinline__ unsigned packbf(float a, float b) {
  __hip_bfloat162 h2 = __float22bfloat162_rn(make_float2(a, b));
  return *(unsigned*)&h2;
}

// ------- fused normalize: stats + normalize + transpose + bf16 cast --------
__global__ void norm_fused(const float* __restrict__ t_in,
                           const float* __restrict__ s_in,
                           const float* __restrict__ r_in,
                           u16* __restrict__ qn, u16* __restrict__ ksn,
                           u16* __restrict__ krn) {
  __shared__ float tile[256 * 33];
  __shared__ float sums[256], sqs[256];
  __shared__ float mv[32], ivv[32];
  int idx = blockIdx.x;
  int ab = idx >> 7, lt = idx & 127;
  int arr = ab >> 1, b = ab & 1;
  int l0 = lt * 32;
  const float* inp = (arr == 0 ? t_in : arr == 1 ? s_in : r_in) + (size_t)b * CDIM * LPOS;
  u16* outp = (arr == 0 ? qn : arr == 1 ? ksn : krn) + (size_t)b * LPOS * CDIM;
  int t = threadIdx.x;
  int cg = t >> 5, l = t & 31;
  float sum = 0.f, sq = 0.f;
#pragma unroll 8
  for (int cc = 0; cc < 32; ++cc) {
    int c = cg * 32 + cc;
    float v = inp[(size_t)c * LPOS + l0 + l];
    tile[c * 33 + l] = v;
    sum += v; sq += v * v;
  }
  sums[t] = sum; sqs[t] = sq;
  __syncthreads();
  if (t < 32) {
    float s = 0.f, q = 0.f;
#pragma unroll
    for (int g = 0; g < 8; ++g) { s += sums[g * 32 + t]; q += sqs[g * 32 + t]; }
    float mean = s * (1.0f / CDIM);
    float nsq = q - s * s * (1.0f / CDIM);
    mv[t] = mean;
    ivv[t] = rsqrtf(fmaxf(nsq, 1e-20f));
  }
  __syncthreads();
  int c2 = t & 127, ph = t >> 7;
#pragma unroll 4
  for (int rr = 0; rr < 16; ++rr) {
    int pos = ph + rr * 2;
    float m = mv[pos], iv = ivv[pos];
    float v0 = (tile[(2 * c2) * 33 + pos] - m) * iv;
    float v1 = (tile[(2 * c2 + 1) * 33 + pos] - m) * iv;
    *(unsigned*)&outp[(size_t)(l0 + pos) * CDIM + 2 * c2] = packbf(v0, v1);
  }
}

// ---------------- build combined V tensors (bf16, [C_v][L]) -----------------
// vs: [2][32][4096]   ch: 0..3 src_feats, 4 ones, 5..31 zero
// vr: [2][160][4096]  ch: 0..150 sem, 151..154 ref_feats, 155 ones, 156..159 zero
__global__ void build_v(const float* __restrict__ sf, const float* __restrict__ rf,
                        const float* __restrict__ sem,
                        u16* __restrict__ vs, u16* __restrict__ vr) {
  int t = blockIdx.x * 256 + threadIdx.x;
  const int NVS = 2 * 32 * 4096;
  if (t < NVS) {
    int b = t >> 17;
    int c = (t >> 12) & 31;
    int j = t & 4095;
    float v = (c < 4) ? sf[((size_t)b * 4 + c) * LPOS + j] : (c == 4 ? 1.0f : 0.0f);
    vs[t] = (u16)f2bfbits(v);
  } else {
    int t2 = t - NVS;
    if (t2 < 2 * 160 * 4096) {
      int b = t2 / (160 * 4096);
      int rr = t2 % (160 * 4096);
      int c = rr >> 12, j = rr & 4095;
      float v = (c < 151) ? sem[((size_t)b * 151 + c) * LPOS + j]
              : (c < 155) ? rf[((size_t)b * 4 + (c - 151)) * LPOS + j]
              : (c == 155) ? 1.0f : 0.0f;
      vr[((size_t)b * 160 + c) * LPOS + j] = (u16)f2bfbits(v);
    }
  }
}

// ---------------- fused flash soft-warp ----------------
// S^T orientation: D[m=j][n=i] = sum_c K[j][c] * Q[i][c]
// PV: D[m=c][n=i]  = sum_j V[c][j] * P[j][i]   (V in registers, A-operand)
// Pipeline: one __syncthreads per iter; K-prefetch issued AFTER the barrier
// into the just-freed buffer -> full compute phase in flight before the next
// barrier's vmcnt(0) drain. V loads issued BEFORE the stage (FIFO: waiting on
// V leaves the K-prefetch outstanding).
template <int CT>
__device__ __forceinline__ void flash_body(
    const u16* __restrict__ qb, const u16* __restrict__ kb,
    const u16* __restrict__ vb, float* __restrict__ dst,
    u16 (*lds_k)[32 * 256], int wave, int lane, int i_wave, int j_base, int iters) {
  int h = lane >> 5, ln = lane & 31;

  // Q fragments register-resident: B[k=c][n=i], lane n=ln, k = kt*16 + h*8 + t
  bf16x8 qf[16];
  const u16* qrow = qb + (size_t)(i_wave + ln) * CDIM;
#pragma unroll
  for (int kt = 0; kt < 16; ++kt)
    qf[kt] = *(const bf16x8*)(qrow + kt * 16 + h * 8);

  f32x16 O[CT];
#pragma unroll
  for (int c = 0; c < CT; ++c)
#pragma unroll
    for (int t = 0; t < 16; ++t) O[c][t] = 0.0f;

  auto stage = [&](int j0s, int buf) {
#pragma unroll
    for (int g = 0; g < 4; ++g) {
      int G = wave * 4 + g;
      int j = 2 * G + h;
      GLOAD_LDS16(kb + (size_t)(j0s + j) * CDIM + (ln ^ (j & 7)) * 8,
                  &lds_k[buf][G * 512]);
    }
  };

  // K ds_read swizzled base (u16 elements): addr(kt) = base + 16*((kt&3)^q) + 64*(kt>>2)
  int kread_base = ln * 256 + 8 * (h ^ (ln & 1));
  int q = (ln >> 1) & 3;

  stage(j_base, 0);

  for (int jt = 0; jt < iters; ++jt) {
    int cur = jt & 1;
    int j0 = j_base + jt * 32;
    __syncthreads();            // drains K(jt) — in flight for a full iteration
    // V kt=0 group -> regs, BEFORE the stage (drain-safe FIFO position)
    bf16x8 vf0[CT], vf1[CT];
#pragma unroll
    for (int ct = 0; ct < CT; ++ct)
      vf0[ct] = *(const bf16x8*)(vb + (size_t)(ct * 32 + ln) * LPOS + j0 + h * 8);
    if (jt + 1 < iters) stage(j0 + 32, cur ^ 1);   // prefetch: in flight until next barrier
    const u16* lk = lds_k[cur];

    // QK: A = K (LDS, swizzled), B = Q (regs)
    f32x16 S;
    if (CT == 1) {              // src: 2-way split accumulator chain
      f32x16 Sa, Sb;
#pragma unroll
      for (int t = 0; t < 16; ++t) { Sa[t] = 0.0f; Sb[t] = 0.0f; }
#pragma unroll
      for (int kt = 0; kt < 16; kt += 2) {
        bf16x8 ka0 = *(const bf16x8*)&lk[kread_base + 16 * ((kt & 3) ^ q) + 64 * (kt >> 2)];
        Sa = __builtin_amdgcn_mfma_f32_32x32x16_bf16(ka0, qf[kt], Sa, 0, 0, 0);
        bf16x8 ka1 = *(const bf16x8*)&lk[kread_base + 16 * (((kt + 1) & 3) ^ q) + 64 * ((kt + 1) >> 2)];
        Sb = __builtin_amdgcn_mfma_f32_32x32x16_bf16(ka1, qf[kt + 1], Sb, 0, 0, 0);
      }
#pragma unroll
      for (int t = 0; t < 16; ++t) S[t] = Sa[t] + Sb[t];
    } else {                    // ref: single chain (register budget)
#pragma unroll
      for (int t = 0; t < 16; ++t) S[t] = 0.0f;
#pragma unroll
      for (int kt = 0; kt < 16; ++kt) {
        bf16x8 ka = *(const bf16x8*)&lk[kread_base + 16 * ((kt & 3) ^ q) + 64 * (kt >> 2)];
        S = __builtin_amdgcn_mfma_f32_32x32x16_bf16(ka, qf[kt], S, 0, 0, 0);
      }
    }
    // V kt=1 group (late: caps live VGPRs; stage is ~QK-phase old by now)
#pragma unroll
    for (int ct = 0; ct < CT; ++ct)
      vf1[ct] = *(const bf16x8*)(vb + (size_t)(ct * 32 + ln) * LPOS + j0 + (2 + h) * 8);

    // cosine sims in [-1,1]: exp directly, no max-subtract needed
#pragma unroll
    for (int t = 0; t < 16; ++t) S[t] = __expf(S[t]);

    // P^T C-layout -> PV B-frags via xor-32 lane exchange, cast to bf16
    bf16x8 pb[2];
#pragma unroll
    for (int kt = 0; kt < 2; ++kt) {
      int kbase = kt * 8 + (h ? 4 : 0);
      int sbase = kt * 8 + (h ? 0 : 4);
      unsigned keep0 = packbf(S[kbase + 0], S[kbase + 1]);
      unsigned keep1 = packbf(S[kbase + 2], S[kbase + 3]);
      unsigned send0 = packbf(S[sbase + 0], S[sbase + 1]);
      unsigned send1 = packbf(S[sbase + 2], S[sbase + 3]);
      unsigned recv0 = (unsigned)__shfl_xor((int)send0, 32, 64);
      unsigned recv1 = (unsigned)__shfl_xor((int)send1, 32, 64);
      union { unsigned u[4]; bf16x8 v; } tmp;
      tmp.u[0] = h ? recv0 : keep0;
      tmp.u[1] = h ? recv1 : keep1;
      tmp.u[2] = h ? keep0 : recv0;
      tmp.u[3] = h ? keep1 : recv1;
      pb[kt] = tmp.v;
    }

    // PV: A = V (regs), B = P
#pragma unroll
    for (int ct = 0; ct < CT; ++ct) {
      O[ct] = __builtin_amdgcn_mfma_f32_32x32x16_bf16(vf0[ct], pb[0], O[ct], 0, 0, 0);
      O[ct] = __builtin_amdgcn_mfma_f32_32x32x16_bf16(vf1[ct], pb[1], O[ct], 0, 0, 0);
    }
  }

  // epilogue: D rows = c, cols = i
#pragma unroll
  for (int ct = 0; ct < CT; ++ct)
#pragma unroll
    for (int t = 0; t < 16; ++t) {
      int c = ct * 32 + (t & 3) + 8 * (t >> 2) + 4 * h;
      dst[(size_t)c * LPOS + i_wave + ln] = O[ct][t];
    }
}

// src: ~150 unified regs -> 3 waves/SIMD allowed
__global__ __launch_bounds__(256, 3) void flash_src(
    const u16* __restrict__ qn, const u16* __restrict__ ksn,
    const u16* __restrict__ vs, float* __restrict__ nsrc, int nchunks) {
  __shared__ u16 lds_k[2][32 * 256];   // 32 KB
  int tid = threadIdx.x;
  int wave = tid >> 6, lane = tid & 63;
  int r = blockIdx.x;
  int chunk = r >> 6, b = (r >> 5) & 1, wgi = r & 31;
  int jchunk = LPOS / nchunks;
  int iters = jchunk / 32;
  int i_wave = wgi * 128 + wave * 32;
  flash_body<1>(qn + (size_t)b * LPOS * CDIM, ksn + (size_t)b * LPOS * CDIM,
                vs + (size_t)b * 32 * LPOS,
                nsrc + (size_t)(chunk * 2 + b) * 32 * LPOS,
                lds_k, wave, lane, i_wave, chunk * jchunk, iters);
}

// ref: ~246 unified regs -> 2 waves/SIMD; single-S chain keeps it under 256
__global__ __launch_bounds__(256, 2) void flash_ref(
    const u16* __restrict__ qn, const u16* __restrict__ krn,
    const u16* __restrict__ vr, float* __restrict__ nref, int nchunks) {
  __shared__ u16 lds_k[2][32 * 256];   // 32 KB
  int tid = threadIdx.x;
  int wave = tid >> 6, lane = tid & 63;
  int r = blockIdx.x;
  int chunk = r >> 6, b = (r >> 5) & 1, wgi = r & 31;
  int jchunk = LPOS / nchunks;
  int iters = jchunk / 32;
  int i_wave = wgi * 128 + wave * 32;
  flash_body<5>(qn + (size_t)b * LPOS * CDIM, krn + (size_t)b * LPOS * CDIM,
                vr + (size_t)b * 160 * LPOS,
                nref + (size_t)(chunk * 2 + b) * 160 * LPOS,
                lds_k, wave, lane, i_wave, chunk * jchunk, iters);
}

// ---------------- finalize: sum chunks, divide by ones-channel --------------
#define NCH_SRC 8
__global__ void finalize(const float* __restrict__ nsrc, const float* __restrict__ nref,
                         float* __restrict__ out, int nch_ref) {
  int t = blockIdx.x * 256 + threadIdx.x;
  if (t >= 1302528) return;
  if (t < 32768) {                        // warped_src_feat [2][4][4096]
    int b = t >> 14, c = (t >> 12) & 3, i = t & 4095;
    float num = 0.f, den = 0.f;
    for (int k = 0; k < NCH_SRC; ++k) {
      const float* base = nsrc + ((size_t)(k * 2 + b) * 32) * LPOS;
      num += base[(size_t)c * LPOS + i];
      den += base[(size_t)4 * LPOS + i];
    }
    out[t] = num / den;
  } else if (t < 65536) {                 // warped_ref_feat [2][4][4096]
    int t1 = t - 32768;
    int b = t1 >> 14, c = (t1 >> 12) & 3, i = t1 & 4095;
    float num = 0.f, den = 0.f;
    for (int k = 0; k < nch_ref; ++k) {
      const float* base = nref + ((size_t)(k * 2 + b) * 160) * LPOS;
      num += base[(size_t)(151 + c) * LPOS + i];
      den += base[(size_t)155 * LPOS + i];
    }
    out[t] = num / den;
  } else {                                // warped_ref_seg [2][151][4096]
    int t2 = t - 65536;
    int b = t2 / 618496;
    int rr = t2 % 618496;
    int c = rr >> 12, i = rr & 4095;
    float num = 0.f, den = 0.f;
    for (int k = 0; k < nch_ref; ++k) {
      const float* base = nref + ((size_t)(k * 2 + b) * 160) * LPOS;
      num += base[(size_t)c * LPOS + i];
      den += base[(size_t)155 * LPOS + i];
    }
    out[t] = num / den;
  }
}

extern "C" void kernel_launch(void* const* d_in, const int* in_sizes, int n_in,
                              void* d_out, int out_size, void* d_ws, size_t ws_size,
                              hipStream_t stream) {
  const float* trg  = (const float*)d_in[0];
  const float* srcp = (const float*)d_in[1];
  const float* refp = (const float*)d_in[2];
  const float* sfeat = (const float*)d_in[3];
  const float* rfeat = (const float*)d_in[4];
  const float* rsem  = (const float*)d_in[5];
  float* out = (float*)d_out;

  char* ws = (char*)d_ws;
  size_t o = 0;
  auto alloc = [&](size_t bytes) -> char* {
    char* p = ws + o;
    o += (bytes + 255) & ~(size_t)255;
    return p;
  };
  u16* qn  = (u16*)alloc(2ull * LPOS * CDIM * 2);
  u16* ksn = (u16*)alloc(2ull * LPOS * CDIM * 2);
  u16* krn = (u16*)alloc(2ull * LPOS * CDIM * 2);
  u16* vs  = (u16*)alloc(2ull * 32 * LPOS * 2);
  u16* vr  = (u16*)alloc(2ull * 160 * LPOS * 2);

  size_t fixed = o;
  size_t nsrc_bytes = (size_t)NCH_SRC * 2 * 32 * LPOS * 4;
  int nch_ref = 8;
  while (nch_ref > 1) {
    size_t need = fixed + 512 + nsrc_bytes +
                  (size_t)nch_ref * 2 * 160 * LPOS * 4;
    if (need <= ws_size) break;
    nch_ref >>= 1;
  }
  float* nsrc = (float*)alloc(nsrc_bytes);
  float* nref = (float*)alloc((size_t)nch_ref * 2 * 160 * LPOS * 4);

  hipLaunchKernelGGL(norm_fused, dim3(768), dim3(256), 0, stream,
                     trg, srcp, refp, qn, ksn, krn);
  hipLaunchKernelGGL(build_v, dim3(6144), dim3(256), 0, stream,
                     sfeat, rfeat, rsem, vs, vr);
  hipLaunchKernelGGL(flash_src, dim3(64 * NCH_SRC), dim3(256), 0, stream,
                     qn, ksn, vs, nsrc, NCH_SRC);
  hipLaunchKernelGGL(flash_ref, dim3(64 * nch_ref), dim3(256), 0, stream,
                     qn, krn, vr, nref, nch_ref);
  hipLaunchKernelGGL(finalize, dim3(5088), dim3(256), 0, stream,
                     nsrc, nref, out, nch_ref);
}

// Round 5
// 201.689 us; speedup vs baseline: 1.8626x; 1.0757x over previous
//
#include <hip/hip_runtime.h>
#include <hip/hip_bf16.h>
#include <cstdint>
#include <cstddef>

typedef unsigned short u16;
typedef __attribute__((ext_vector_type(8))) __bf16 bf16x8;
typedef __attribute__((ext_vector_type(16))) float f32x16;

#define LPOS 4096
#define CDIM 256
#define NCH 8

// async global->LDS 16B: LDS dst must be wave-uniform base + lane*16
#define GLOAD_LDS16(g, l)                                                      \
  __builtin_amdgcn_global_load_lds(                                            \
      (const __attribute__((address_space(1))) void*)(g),                      \
      (__attribute__((address_space(3))) void*)(l), 16, 0, 0)

__device__ __forceinline__ unsigned f2bfbits(float x) {
  union { float f; unsigned u; } v; v.f = x;
  return (v.u + 0x7FFFu + ((v.u >> 16) & 1u)) >> 16;
}
__device__ __forceinline__ unsigned packbf(float a, float b) {
  __hip_bfloat162 h2 = __float22bfloat162_rn(make_float2(a, b));
  return *(unsigned*)&h2;
}

// ------- fused normalize: stats + normalize + transpose + bf16 cast --------
__global__ void norm_fused(const float* __restrict__ t_in,
                           const float* __restrict__ s_in,
                           const float* __restrict__ r_in,
                           u16* __restrict__ qn, u16* __restrict__ ksn,
                           u16* __restrict__ krn) {
  __shared__ float tile[256 * 33];
  __shared__ float sums[256], sqs[256];
  __shared__ float mv[32], ivv[32];
  int idx = blockIdx.x;
  int ab = idx >> 7, lt = idx & 127;
  int arr = ab >> 1, b = ab & 1;
  int l0 = lt * 32;
  const float* inp = (arr == 0 ? t_in : arr == 1 ? s_in : r_in) + (size_t)b * CDIM * LPOS;
  u16* outp = (arr == 0 ? qn : arr == 1 ? ksn : krn) + (size_t)b * LPOS * CDIM;
  int t = threadIdx.x;
  int cg = t >> 5, l = t & 31;
  float sum = 0.f, sq = 0.f;
#pragma unroll 8
  for (int cc = 0; cc < 32; ++cc) {
    int c = cg * 32 + cc;
    float v = inp[(size_t)c * LPOS + l0 + l];
    tile[c * 33 + l] = v;
    sum += v; sq += v * v;
  }
  sums[t] = sum; sqs[t] = sq;
  __syncthreads();
  if (t < 32) {
    float s = 0.f, q = 0.f;
#pragma unroll
    for (int g = 0; g < 8; ++g) { s += sums[g * 32 + t]; q += sqs[g * 32 + t]; }
    float mean = s * (1.0f / CDIM);
    float nsq = q - s * s * (1.0f / CDIM);
    mv[t] = mean;
    ivv[t] = rsqrtf(fmaxf(nsq, 1e-20f));
  }
  __syncthreads();
  int c2 = t & 127, ph = t >> 7;
#pragma unroll 4
  for (int rr = 0; rr < 16; ++rr) {
    int pos = ph + rr * 2;
    float m = mv[pos], iv = ivv[pos];
    float v0 = (tile[(2 * c2) * 33 + pos] - m) * iv;
    float v1 = (tile[(2 * c2 + 1) * 33 + pos] - m) * iv;
    *(unsigned*)&outp[(size_t)(l0 + pos) * CDIM + 2 * c2] = packbf(v0, v1);
  }
}

// ---------------- build combined V tensors (bf16, [C_v][L]) -----------------
// vs: [2][32][4096]   ch: 0..3 src_feats, 4 ones, 5..31 zero
// vr: [2][192][4096]  ch: 0..150 sem, 151..154 ref_feats, 155 ones,
//     156..159 zero; rows 160..191 are alloc padding (staged but never used)
__global__ void build_v(const float* __restrict__ sf, const float* __restrict__ rf,
                        const float* __restrict__ sem,
                        u16* __restrict__ vs, u16* __restrict__ vr) {
  int t = blockIdx.x * 256 + threadIdx.x;
  const int NVS = 2 * 32 * 4096;
  if (t < NVS) {
    int b = t >> 17;
    int c = (t >> 12) & 31;
    int j = t & 4095;
    float v = (c < 4) ? sf[((size_t)b * 4 + c) * LPOS + j] : (c == 4 ? 1.0f : 0.0f);
    vs[t] = (u16)f2bfbits(v);
  } else {
    int t2 = t - NVS;
    if (t2 < 2 * 160 * 4096) {
      int b = t2 / (160 * 4096);
      int rr = t2 % (160 * 4096);
      int c = rr >> 12, j = rr & 4095;
      float v = (c < 151) ? sem[((size_t)b * 151 + c) * LPOS + j]
              : (c < 155) ? rf[((size_t)b * 4 + (c - 151)) * LPOS + j]
              : (c == 155) ? 1.0f : 0.0f;
      vr[((size_t)b * 192 + c) * LPOS + j] = (u16)f2bfbits(v);
    }
  }
}

// ---------------- fused flash soft-warp, merged src+ref ---------------------
// S^T orientation: D[m=j][n=i] = sum_c K[j][c] * Q[i][c]
// PV: D[m=c][n=i]  = sum_j V[c][j] * P[j][i]
// FIFO discipline (the R4 bug fix): ALL consumer global loads for iteration jt
// are issued BEFORE the producer prefetch of jt+1. The only vmcnt(0) is the
// __syncthreads drain, by which time the prefetch has a full iteration in
// flight. Ref has NO consumer loads at all (V staged in LDS with K).
// MT = j-tiles per iteration (j-width 32*MT). Ref: MT=1 CT=5. Src: MT=2 CT=1.
template <int CT, int MT>
__device__ __forceinline__ void flash_body(
    const u16* __restrict__ qb, const u16* __restrict__ kb,
    const u16* __restrict__ vb, float* __restrict__ dst,
    u16 (*lds)[64 * 256], int wave, int lane, int i_wave, int j_base, int iters) {
  int h = lane >> 5, ln = lane & 31;

  // Q fragments register-resident: B[k=c][n=i], lane n=ln, k = kt*16 + h*8 + t
  bf16x8 qf[16];
  const u16* qrow = qb + (size_t)(i_wave + ln) * CDIM;
#pragma unroll
  for (int kt = 0; kt < 16; ++kt)
    qf[kt] = *(const bf16x8*)(qrow + kt * 16 + h * 8);

  f32x16 O[CT];
#pragma unroll
  for (int c = 0; c < CT; ++c)
#pragma unroll
    for (int t = 0; t < 16; ++t) O[c][t] = 0.0f;

  // Producer: K rows (XOR-swizzled 16B chunks) + (ref) V planes into the
  // 16 KB hole above ref's 32 K-rows. All dsts are uniform-base + lane*16.
  auto stage = [&](int j0s, int buf) {
#pragma unroll
    for (int g = 0; g < 4 * MT; ++g) {
      int G = wave * 4 * MT + g;
      int j = 2 * G + h;
      GLOAD_LDS16(kb + (size_t)(j0s + j) * CDIM + (ln ^ (j & 7)) * 8,
                  &lds[buf][G * 512]);
    }
    if constexpr (CT == 5) {
#pragma unroll
      for (int g = 0; g < 3; ++g) {
        int t2 = wave * 3 + g;              // 0..11
        int p = t2 & 3, cc = t2 >> 2;
        int c = cc * 64 + lane;             // 0..191 (rows 160..191: pad, unread)
        GLOAD_LDS16(vb + (size_t)c * LPOS + j0s + p * 8,
                    &lds[buf][8192 + p * 1536 + cc * 512]);
      }
    }
  };

  // K ds_read swizzle (validated R4): row r=mt*32+ln, chunk kt at
  // base + 16*((kt&3)^q) + 64*(kt>>2), q=(ln>>1)&3
  int kread_base = ln * 256 + 8 * (h ^ (ln & 1));
  int q = (ln >> 1) & 3;

  stage(j_base, 0);

  for (int jt = 0; jt < iters; ++jt) {
    int cur = jt & 1;
    int j0 = j_base + jt * 32 * MT;
    __syncthreads();            // drains prefetch(jt) — in flight a full iter

    // src: consumer V loads FIRST (before producer stage -> FIFO-safe)
    bf16x8 vf[2 * MT][CT];
    if constexpr (CT != 5) {
#pragma unroll
      for (int kt2 = 0; kt2 < 2 * MT; ++kt2)
#pragma unroll
        for (int ct = 0; ct < CT; ++ct)
          vf[kt2][ct] = *(const bf16x8*)(vb + (size_t)(ct * 32 + ln) * LPOS +
                                         j0 + (2 * kt2 + h) * 8);
    }
    if (jt + 1 < iters) stage(j0 + 32 * MT, cur ^ 1);   // producer LAST
    const u16* lk = lds[cur];

    // QK: A = K (LDS, swizzled), B = Q (regs); MT independent chains
    f32x16 S[MT];
#pragma unroll
    for (int mt = 0; mt < MT; ++mt)
#pragma unroll
      for (int t = 0; t < 16; ++t) S[mt][t] = 0.0f;
#pragma unroll
    for (int kt = 0; kt < 16; ++kt)
#pragma unroll
      for (int mt = 0; mt < MT; ++mt) {
        bf16x8 ka = *(const bf16x8*)&lk[mt * 8192 + kread_base +
                                        16 * ((kt & 3) ^ q) + 64 * (kt >> 2)];
        S[mt] = __builtin_amdgcn_mfma_f32_32x32x16_bf16(ka, qf[kt], S[mt], 0, 0, 0);
      }

    // cosine sims in [-1,1]: exp directly, no max-subtract needed
#pragma unroll
    for (int mt = 0; mt < MT; ++mt)
#pragma unroll
      for (int t = 0; t < 16; ++t) S[mt][t] = __expf(S[mt][t]);

    // P^T C-layout -> PV B-frags via xor-32 lane exchange, cast to bf16
    bf16x8 pb[2 * MT];
#pragma unroll
    for (int kt2 = 0; kt2 < 2 * MT; ++kt2) {
      int mt = kt2 >> 1, kh = kt2 & 1;
      int kbase = kh * 8 + (h ? 4 : 0);
      int sbase = kh * 8 + (h ? 0 : 4);
      unsigned keep0 = packbf(S[mt][kbase + 0], S[mt][kbase + 1]);
      unsigned keep1 = packbf(S[mt][kbase + 2], S[mt][kbase + 3]);
      unsigned send0 = packbf(S[mt][sbase + 0], S[mt][sbase + 1]);
      unsigned send1 = packbf(S[mt][sbase + 2], S[mt][sbase + 3]);
      unsigned recv0 = (unsigned)__shfl_xor((int)send0, 32, 64);
      unsigned recv1 = (unsigned)__shfl_xor((int)send1, 32, 64);
      union { unsigned u[4]; bf16x8 v; } tmp;
      tmp.u[0] = h ? recv0 : keep0;
      tmp.u[1] = h ? recv1 : keep1;
      tmp.u[2] = h ? keep0 : recv0;
      tmp.u[3] = h ? keep1 : recv1;
      pb[kt2] = tmp.v;
    }

    // PV: A = V (ref: LDS hole; src: regs), B = P
#pragma unroll
    for (int ct = 0; ct < CT; ++ct)
#pragma unroll
      for (int kt2 = 0; kt2 < 2 * MT; ++kt2) {
        bf16x8 va;
        if constexpr (CT == 5)
          va = *(const bf16x8*)&lk[8192 + (2 * kt2 + h) * 1536 + (ct * 32 + ln) * 8];
        else
          va = vf[kt2][ct];
        O[ct] = __builtin_amdgcn_mfma_f32_32x32x16_bf16(va, pb[kt2], O[ct], 0, 0, 0);
      }
  }

  // epilogue: D rows = c, cols = i
#pragma unroll
  for (int ct = 0; ct < CT; ++ct)
#pragma unroll
    for (int t = 0; t < 16; ++t) {
      int c = ct * 32 + (t & 3) + 8 * (t >> 2) + 4 * h;
      dst[(size_t)c * LPOS + i_wave + ln] = O[ct][t];
    }
}

// merged dispatch: even idx -> ref block, odd idx -> src block (interleaved so
// each CU co-schedules one of each; they fill each other's latency bubbles).
__global__ __launch_bounds__(256, 2) void flash(
    const u16* __restrict__ qn, const u16* __restrict__ ksn, const u16* __restrict__ krn,
    const u16* __restrict__ vs, const u16* __restrict__ vr,
    float* __restrict__ nsrc, float* __restrict__ nref, int nch_ref) {
  __shared__ u16 lds[2][64 * 256];   // 64 KB: src K 64 rows; ref K 32 rows + V hole
  int tid = threadIdx.x;
  int wave = tid >> 6, lane = tid & 63;
  int idx = blockIdx.x;
  int nref_blocks = 64 * nch_ref;
  bool is_src;
  int r;
  if (idx < 2 * nref_blocks) { is_src = idx & 1; r = idx >> 1; }
  else                       { is_src = true;    r = idx - nref_blocks; }
  int chunk = r >> 6, b = (r >> 5) & 1, wgi = r & 31;
  int i_wave = wgi * 128 + wave * 32;
  const u16* qb = qn + (size_t)b * LPOS * CDIM;
  if (is_src) {
    // src: jchunk=512, MT=2 (j-tile 64) -> 8 iters
    flash_body<1, 2>(qb, ksn + (size_t)b * LPOS * CDIM, vs + (size_t)b * 32 * LPOS,
                     nsrc + (size_t)(chunk * 2 + b) * 32 * LPOS,
                     lds, wave, lane, i_wave, chunk * 512, 8);
  } else {
    int jchunk = LPOS / nch_ref;
    flash_body<5, 1>(qb, krn + (size_t)b * LPOS * CDIM, vr + (size_t)b * 192 * LPOS,
                     nref + (size_t)(chunk * 2 + b) * 160 * LPOS,
                     lds, wave, lane, i_wave, chunk * jchunk, jchunk / 32);
  }
}

// ---------------- finalize: sum chunks, divide by ones-channel --------------
__global__ void finalize(const float* __restrict__ nsrc, const float* __restrict__ nref,
                         float* __restrict__ out, int nch_ref) {
  int t = blockIdx.x * 256 + threadIdx.x;
  if (t >= 1302528) return;
  if (t < 32768) {                        // warped_src_feat [2][4][4096]
    int b = t >> 14, c = (t >> 12) & 3, i = t & 4095;
    float num = 0.f, den = 0.f;
    for (int k = 0; k < NCH; ++k) {
      const float* base = nsrc + ((size_t)(k * 2 + b) * 32) * LPOS;
      num += base[(size_t)c * LPOS + i];
      den += base[(size_t)4 * LPOS + i];
    }
    out[t] = num / den;
  } else if (t < 65536) {                 // warped_ref_feat [2][4][4096]
    int t1 = t - 32768;
    int b = t1 >> 14, c = (t1 >> 12) & 3, i = t1 & 4095;
    float num = 0.f, den = 0.f;
    for (int k = 0; k < nch_ref; ++k) {
      const float* base = nref + ((size_t)(k * 2 + b) * 160) * LPOS;
      num += base[(size_t)(151 + c) * LPOS + i];
      den += base[(size_t)155 * LPOS + i];
    }
    out[t] = num / den;
  } else {                                // warped_ref_seg [2][151][4096]
    int t2 = t - 65536;
    int b = t2 / 618496;
    int rr = t2 % 618496;
    int c = rr >> 12, i = rr & 4095;
    float num = 0.f, den = 0.f;
    for (int k = 0; k < nch_ref; ++k) {
      const float* base = nref + ((size_t)(k * 2 + b) * 160) * LPOS;
      num += base[(size_t)c * LPOS + i];
      den += base[(size_t)155 * LPOS + i];
    }
    out[t] = num / den;
  }
}

extern "C" void kernel_launch(void* const* d_in, const int* in_sizes, int n_in,
                              void* d_out, int out_size, void* d_ws, size_t ws_size,
                              hipStream_t stream) {
  const float* trg  = (const float*)d_in[0];
  const float* srcp = (const float*)d_in[1];
  const float* refp = (const float*)d_in[2];
  const float* sfeat = (const float*)d_in[3];
  const float* rfeat = (const float*)d_in[4];
  const float* rsem  = (const float*)d_in[5];
  float* out = (float*)d_out;

  char* ws = (char*)d_ws;
  size_t o = 0;
  auto alloc = [&](size_t bytes) -> char* {
    char* p = ws + o;
    o += (bytes + 255) & ~(size_t)255;
    return p;
  };
  u16* qn  = (u16*)alloc(2ull * LPOS * CDIM * 2);
  u16* ksn = (u16*)alloc(2ull * LPOS * CDIM * 2);
  u16* krn = (u16*)alloc(2ull * LPOS * CDIM * 2);
  u16* vs  = (u16*)alloc(2ull * 32 * LPOS * 2);
  u16* vr  = (u16*)alloc(2ull * 192 * LPOS * 2);   // 192: +32 pad rows for stage

  size_t fixed = o;
  size_t nsrc_bytes = (size_t)NCH * 2 * 32 * LPOS * 4;
  int nch_ref = NCH;
  while (nch_ref > 1) {
    size_t need = fixed + 512 + nsrc_bytes +
                  (size_t)nch_ref * 2 * 160 * LPOS * 4;
    if (need <= ws_size) break;
    nch_ref >>= 1;
  }
  float* nsrc = (float*)alloc(nsrc_bytes);
  float* nref = (float*)alloc((size_t)nch_ref * 2 * 160 * LPOS * 4);

  hipLaunchKernelGGL(norm_fused, dim3(768), dim3(256), 0, stream,
                     trg, srcp, refp, qn, ksn, krn);
  hipLaunchKernelGGL(build_v, dim3(6144), dim3(256), 0, stream,
                     sfeat, rfeat, rsem, vs, vr);
  hipLaunchKernelGGL(flash, dim3(512 + 64 * nch_ref), dim3(256), 0, stream,
                     qn, ksn, krn, vs, vr, nsrc, nref, nch_ref);
  hipLaunchKernelGGL(finalize, dim3(5088), dim3(256), 0, stream,
                     nsrc, nref, out, nch_ref);
}